// Round 3
// baseline (558.113 us; speedup 1.0000x reference)
//
#include <hip/hip_runtime.h>
#include <math.h>

#define NP   132
#define NV   67            // Hermitian half-spectrum (0..66), 66 = Nyquist
#define NPP  (NP*NP)       // 17424
#define NCH  64
#define NIMG 256
#define NX   128
#define NO   256
#define TWO_PI 6.2831853071795864769f

// ws layout (floats):
//   H   : [NCH ][NV][NP][2]   per-channel transfer fn, transposed [v][u]
//   A   : [NIMG][NP][NV][2]   row-DFT of y
//   T   : [NIMG][NV][NP][2]   H * col-DFT, transposed [v][u]
//   U   : [NIMG][NV][NP][2]   col-inverse, transposed [v][n0]
//   rho : [NIMG][NPP]         real correction image
static const size_t OFF_H   = 0;
static const size_t OFF_A   = OFF_H + (size_t)NCH*NV*NP*2;
static const size_t OFF_T   = OFF_A + (size_t)NIMG*NP*NV*2;
static const size_t OFF_U   = OFF_T + (size_t)NIMG*NV*NP*2;
static const size_t OFF_RHO = OFF_U + (size_t)NIMG*NV*NP*2;

__global__ __launch_bounds__(256) void k_compute_H(
    const float* __restrict__ wgt, const float* __restrict__ bias,
    float2* __restrict__ H) {
  int idx = blockIdx.x * 256 + threadIdx.x;   // over NV*NP
  int c = blockIdx.y;
  if (idx >= NV*NP) return;
  int u = idx % NP, v = idx / NP;
  float k[3][3];
#pragma unroll
  for (int i = 0; i < 3; i++)
#pragma unroll
    for (int j = 0; j < 3; j++) k[i][j] = wgt[c*9 + i*3 + j];
  float invW = 0.f;
#pragma unroll
  for (int p0 = -1; p0 <= 1; p0++)
#pragma unroll
    for (int p1 = -1; p1 <= 1; p1++) {
      float s = 0.f;
#pragma unroll
      for (int i = 0; i < 3; i++)
#pragma unroll
        for (int j = 0; j < 3; j++) {
          int i2 = i - 2*p0, j2 = j - 2*p1;
          if (i2 >= 0 && i2 < 3 && j2 >= 0 && j2 < 3) s += k[i][j]*k[i2][j2];
        }
      float ang = TWO_PI * (float)(u*p0 + v*p1) / (float)NP;
      invW += s * cosf(ang);
    }
  float B00 = k[0][0]+k[0][1]+k[1][0]+k[1][1];
  float B10 = k[2][0]+k[2][1];
  float B01 = k[0][2]+k[1][2];
  float B11 = k[2][2];
  float su, cu, sv, cv, suv, cuv;
  sincosf(TWO_PI*(float)u/(float)NP, &su, &cu);
  sincosf(TWO_PI*(float)v/(float)NP, &sv, &cv);
  sincosf(TWO_PI*(float)(u+v)/(float)NP, &suv, &cuv);
  float Bre = B00 + B10*cu + B01*cv + B11*cuv;
  float Bim = -(B10*su + B01*sv + B11*suv);
  float alpha = 1.f/(1.f + expf(9.f - bias[c])) + 1e-5f;
  float d = invW + alpha;
  H[((size_t)c*NV + v)*NP + u] = make_float2((1.f - Bre)/d, (-Bim)/d);
}

// S1 row-DFT: A[n0][v] = sum_n1 y[n0][n1] W^(v n1). 16 rows/block, lane = (rowgroup, v), 4 rows/lane.
__global__ __launch_bounds__(256) void k_s1(
    const float* __restrict__ x, float2* __restrict__ A) {
  __shared__ float ly4[NP*20];          // [n1][row], 16 used of 20 (pad vs bank conflicts, 16B aligned)
  int tid = threadIdx.x, img = blockIdx.y, n00 = blockIdx.x*16;
  const float* xim = x + (size_t)img*NX*NX;
  for (int e = tid; e < 16*NP; e += 256) {
    int rr = e/NP, n1 = e - rr*NP;
    ly4[n1*20 + rr] = xim[(((n00 + rr + 126) & 127))*NX + ((n1 + 126) & 127)];
  }
  __syncthreads();
  for (int e = tid; e < 268; e += 256) {   // 4 rowgroups x 67 v
    int rg = e/67, v = e - rg*67;
    float s0, c0; sincosf(TWO_PI*(float)v/(float)NP, &s0, &c0);
    float tr = 1.f, ti = 0.f;
    float ar0=0,ai0=0,ar1=0,ai1=0,ar2=0,ai2=0,ar3=0,ai3=0;
    for (int n1 = 0; n1 < NP; n1++) {
      float4 d = *(const float4*)(ly4 + n1*20 + rg*4);
      ar0 += tr*d.x; ai0 -= ti*d.x;
      ar1 += tr*d.y; ai1 -= ti*d.y;
      ar2 += tr*d.z; ai2 -= ti*d.z;
      ar3 += tr*d.w; ai3 -= ti*d.w;
      float ntr = tr*c0 - ti*s0; ti = tr*s0 + ti*c0; tr = ntr;
    }
    float arr[4] = {ar0,ar1,ar2,ar3}, aii[4] = {ai0,ai1,ai2,ai3};
#pragma unroll
    for (int q = 0; q < 4; q++) {
      int row = n00 + rg*4 + q;
      if (row < NP) A[((size_t)img*NP + row)*NV + v] = make_float2(arr[q], aii[q]);
    }
  }
}

// S2 col-DFT + H: T[v][u] = H[c][v][u] * sum_n0 A[n0][v] W^(u n0). 8-wide v-strip, 4 v/lane.
__global__ __launch_bounds__(256) void k_s2(
    const float2* __restrict__ A, const float2* __restrict__ H,
    float2* __restrict__ T) {
  __shared__ float2 la[NP*10];          // [n0][j], 8 used of 10
  int tid = threadIdx.x, img = blockIdx.y, v0 = blockIdx.x*8, c = img & 63;
  for (int e = tid; e < NP*8; e += 256) {
    int n0 = e >> 3, j = e & 7, v = v0 + j;
    la[n0*10 + j] = (v < NV) ? A[((size_t)img*NP + n0)*NV + v] : make_float2(0.f, 0.f);
  }
  __syncthreads();
  for (int e = tid; e < 264; e += 256) {   // 2 jj-groups x 132 u
    int jj = e/132, u = e - jj*132;
    float s0, c0; sincosf(TWO_PI*(float)u/(float)NP, &s0, &c0);
    float tr = 1.f, ti = 0.f;
    float ar0=0,ai0=0,ar1=0,ai1=0,ar2=0,ai2=0,ar3=0,ai3=0;
    for (int n0 = 0; n0 < NP; n0++) {
      const float4* p = (const float4*)(la + n0*10 + jj*4);
      float4 d01 = p[0], d23 = p[1];
      ar0 += d01.x*tr + d01.y*ti;  ai0 += d01.y*tr - d01.x*ti;
      ar1 += d01.z*tr + d01.w*ti;  ai1 += d01.w*tr - d01.z*ti;
      ar2 += d23.x*tr + d23.y*ti;  ai2 += d23.y*tr - d23.x*ti;
      ar3 += d23.z*tr + d23.w*ti;  ai3 += d23.w*tr - d23.z*ti;
      float ntr = tr*c0 - ti*s0; ti = tr*s0 + ti*c0; tr = ntr;
    }
    float arr[4] = {ar0,ar1,ar2,ar3}, aii[4] = {ai0,ai1,ai2,ai3};
#pragma unroll
    for (int q = 0; q < 4; q++) {
      int v = v0 + jj*4 + q;
      if (v < NV) {
        float2 h = H[((size_t)c*NV + v)*NP + u];
        T[((size_t)img*NV + v)*NP + u] =
            make_float2(arr[q]*h.x - aii[q]*h.y, arr[q]*h.y + aii[q]*h.x);
      }
    }
  }
}

// S3 col-inverse: U[v][n0] = sum_u conj(W)^(n0 u) T[v][u]. 8-wide v-strip, 4 v/lane.
__global__ __launch_bounds__(256) void k_s3(
    const float2* __restrict__ T, float2* __restrict__ U) {
  __shared__ float2 lt[NP*10];          // [u][j]
  int tid = threadIdx.x, img = blockIdx.y, v0 = blockIdx.x*8;
  for (int e = tid; e < NP*8; e += 256) {
    int j = e/132, u = e - j*132, v = v0 + j;
    lt[u*10 + j] = (v < NV) ? T[((size_t)img*NV + v)*NP + u] : make_float2(0.f, 0.f);
  }
  __syncthreads();
  for (int e = tid; e < 264; e += 256) {
    int jj = e/132, n0 = e - jj*132;
    float s0, c0; sincosf(TWO_PI*(float)n0/(float)NP, &s0, &c0);
    float tr = 1.f, ti = 0.f;
    float ar0=0,ai0=0,ar1=0,ai1=0,ar2=0,ai2=0,ar3=0,ai3=0;
    for (int u = 0; u < NP; u++) {
      const float4* p = (const float4*)(lt + u*10 + jj*4);
      float4 d01 = p[0], d23 = p[1];
      ar0 += d01.x*tr - d01.y*ti;  ai0 += d01.x*ti + d01.y*tr;
      ar1 += d01.z*tr - d01.w*ti;  ai1 += d01.z*ti + d01.w*tr;
      ar2 += d23.x*tr - d23.y*ti;  ai2 += d23.x*ti + d23.y*tr;
      ar3 += d23.z*tr - d23.w*ti;  ai3 += d23.z*ti + d23.w*tr;
      float ntr = tr*c0 - ti*s0; ti = tr*s0 + ti*c0; tr = ntr;
    }
    float arr[4] = {ar0,ar1,ar2,ar3}, aii[4] = {ai0,ai1,ai2,ai3};
#pragma unroll
    for (int q = 0; q < 4; q++) {
      int v = v0 + jj*4 + q;
      if (v < NV) U[((size_t)img*NV + v)*NP + n0] = make_float2(arr[q], aii[q]);
    }
  }
}

// S4 row real inverse (half-spectrum): 8 rows/block, lane = (rowgroup, n1), 4 rows/lane.
__global__ __launch_bounds__(256) void k_s4(
    const float2* __restrict__ U, float* __restrict__ rho) {
  __shared__ float2 lu[NV*10];          // [v][r], 8 used of 10
  int tid = threadIdx.x, img = blockIdx.y, n00 = blockIdx.x*8;
  for (int e = tid; e < NV*8; e += 256) {
    int v = e >> 3, r = e & 7, n0 = n00 + r;
    lu[v*10 + r] = (n0 < NP) ? U[((size_t)img*NV + v)*NP + n0] : make_float2(0.f, 0.f);
  }
  __syncthreads();
  for (int e = tid; e < 264; e += 256) {
    int rg = e/132, n1 = e - rg*132;
    float s0, c0; sincosf(TWO_PI*(float)n1/(float)NP, &s0, &c0);
    float tr = c0, ti = s0;            // starts at v=1: W^(n1)
    float a0=0,a1=0,a2=0,a3=0;
    for (int v = 1; v < 66; v++) {
      const float4* p = (const float4*)(lu + v*10 + rg*4);
      float4 d01 = p[0], d23 = p[1];
      a0 += d01.x*tr - d01.y*ti;
      a1 += d01.z*tr - d01.w*ti;
      a2 += d23.x*tr - d23.y*ti;
      a3 += d23.z*tr - d23.w*ti;
      float ntr = tr*c0 - ti*s0; ti = tr*s0 + ti*c0; tr = ntr;
    }
    float sgn = (n1 & 1) ? -1.f : 1.f;
    float acc[4] = {a0,a1,a2,a3};
#pragma unroll
    for (int q = 0; q < 4; q++) {
      int r = rg*4 + q, row = n00 + r;
      if (row < NP) {
        float dc = lu[r].x;            // v=0
        float ny = lu[66*10 + r].x;    // v=66 Nyquist
        rho[(size_t)img*NPP + (size_t)row*NP + n1] =
            (dc + sgn*ny + 2.f*acc[q]) * (1.0f/(float)NPP);
      }
    }
  }
}

// epilogue: out = gelu( x_up + subpixel 3x3 taps of K over zero-upsampled rho )
__global__ __launch_bounds__(256) void k_epilogue(
    const float* __restrict__ x, const float* __restrict__ wgt,
    const float* __restrict__ rho, float* __restrict__ out) {
  int idx = blockIdx.x * 256 + threadIdx.x;
  int o1 = idx & 255;
  int o0 = (idx >> 8) & 255;
  int img = idx >> 16;
  int c = img & 63;
  int n0 = (o0 + 4) >> 1, n1 = (o1 + 4) >> 1;
  int p0 = o0 & 1, p1 = o1 & 1;
  const float* rim = rho + (size_t)img*NPP;
  int base = n0*NP + n1;
  float r00 = rim[base], r01 = rim[base+1], r10 = rim[base+NP], r11 = rim[base+NP+1];
  const float* w = wgt + c*9;
  float wa = p0 ? (p1 ? w[0] : w[1]) : (p1 ? w[3] : w[4]);
  float wb = p1 ? (p0 ? w[2] : w[5]) : 0.f;
  float wc = p0 ? (p1 ? w[6] : w[7]) : 0.f;
  float wd = (p0 & p1) ? w[8] : 0.f;
  float S = wa*r00 + wb*r01 + wc*r10 + wd*r11;
  float xv = x[(size_t)img*NX*NX + (n0-2)*NX + (n1-2)];
  float z = xv + S;
  out[idx] = 0.5f*z*(1.0f + erff(z*0.70710678118654752f));
}

extern "C" void kernel_launch(void* const* d_in, const int* in_sizes, int n_in,
                              void* d_out, int out_size, void* d_ws, size_t ws_size,
                              hipStream_t stream) {
  const float* x    = (const float*)d_in[0];
  const float* wgt  = (const float*)d_in[1];
  const float* bias = (const float*)d_in[2];
  float* ws = (float*)d_ws;
  float2* H   = (float2*)(ws + OFF_H);
  float2* A   = (float2*)(ws + OFF_A);
  float2* T   = (float2*)(ws + OFF_T);
  float2* U   = (float2*)(ws + OFF_U);
  float*  rho = ws + OFF_RHO;
  float* out = (float*)d_out;

  k_compute_H<<<dim3((NV*NP + 255)/256, NCH), 256, 0, stream>>>(wgt, bias, H);
  k_s1 <<<dim3(9,  NIMG), 256, 0, stream>>>(x, A);     // 9*16 >= 132 rows
  k_s2 <<<dim3(9,  NIMG), 256, 0, stream>>>(A, H, T);  // 9*8  >= 67 v
  k_s3 <<<dim3(9,  NIMG), 256, 0, stream>>>(T, U);
  k_s4 <<<dim3(17, NIMG), 256, 0, stream>>>(U, rho);   // 17*8 >= 132 rows
  k_epilogue<<<(NIMG*NO*NO)/256, 256, 0, stream>>>(x, wgt, rho, out);
}

// Round 4
// 419.859 us; speedup vs baseline: 1.3293x; 1.3293x over previous
//
#include <hip/hip_runtime.h>
#include <math.h>

#define NP   132
#define NV   67            // Hermitian half-spectrum (0..66), 66 = Nyquist
#define NPP  (NP*NP)       // 17424
#define NCH  64
#define NIMG 256
#define NX   128
#define NO   256
#define TWO_PI 6.2831853071795864769f

// ws layout (floats):
//   H   : [NCH ][NV][NP][2]   per-channel transfer fn, transposed [v][u]
//   A   : [NIMG][NP][NV][2]   row-DFT of y
//   T   : [NIMG][NV][NP][2]   H * col-DFT, transposed [v][u]
//   U   : [NIMG][NV][NP][2]   col-inverse, transposed [v][n0]
//   rho : [NIMG][NPP]         real correction image
static const size_t OFF_H   = 0;
static const size_t OFF_A   = OFF_H + (size_t)NCH*NV*NP*2;
static const size_t OFF_T   = OFF_A + (size_t)NIMG*NP*NV*2;
static const size_t OFF_U   = OFF_T + (size_t)NIMG*NV*NP*2;
static const size_t OFF_RHO = OFF_U + (size_t)NIMG*NV*NP*2;

__global__ __launch_bounds__(256) void k_compute_H(
    const float* __restrict__ wgt, const float* __restrict__ bias,
    float2* __restrict__ H) {
  int idx = blockIdx.x * 256 + threadIdx.x;   // over NV*NP
  int c = blockIdx.y;
  if (idx >= NV*NP) return;
  int u = idx % NP, v = idx / NP;
  float k[3][3];
#pragma unroll
  for (int i = 0; i < 3; i++)
#pragma unroll
    for (int j = 0; j < 3; j++) k[i][j] = wgt[c*9 + i*3 + j];
  float invW = 0.f;
#pragma unroll
  for (int p0 = -1; p0 <= 1; p0++)
#pragma unroll
    for (int p1 = -1; p1 <= 1; p1++) {
      float s = 0.f;
#pragma unroll
      for (int i = 0; i < 3; i++)
#pragma unroll
        for (int j = 0; j < 3; j++) {
          int i2 = i - 2*p0, j2 = j - 2*p1;
          if (i2 >= 0 && i2 < 3 && j2 >= 0 && j2 < 3) s += k[i][j]*k[i2][j2];
        }
      float ang = TWO_PI * (float)(u*p0 + v*p1) / (float)NP;
      invW += s * cosf(ang);
    }
  float B00 = k[0][0]+k[0][1]+k[1][0]+k[1][1];
  float B10 = k[2][0]+k[2][1];
  float B01 = k[0][2]+k[1][2];
  float B11 = k[2][2];
  float su, cu, sv, cv, suv, cuv;
  sincosf(TWO_PI*(float)u/(float)NP, &su, &cu);
  sincosf(TWO_PI*(float)v/(float)NP, &sv, &cv);
  sincosf(TWO_PI*(float)(u+v)/(float)NP, &suv, &cuv);
  float Bre = B00 + B10*cu + B01*cv + B11*cuv;
  float Bim = -(B10*su + B01*sv + B11*suv);
  float alpha = 1.f/(1.f + expf(9.f - bias[c])) + 1e-5f;
  float d = invW + alpha;
  H[((size_t)c*NV + v)*NP + u] = make_float2((1.f - Bre)/d, (-Bim)/d);
}

// S1 row-DFT: A[n0][v] = sum_n1 y[n0][n1] W^(v n1). 16 rows/block, lane = (rowgroup, v), 4 rows/lane.
__global__ __launch_bounds__(256, 4) void k_s1(
    const float* __restrict__ x, float2* __restrict__ A) {
  __shared__ float ly4[NP*20];          // [n1][row], 16 used of 20
  int tid = threadIdx.x, img = blockIdx.y, n00 = blockIdx.x*16;
  const float* xim = x + (size_t)img*NX*NX;
  for (int e = tid; e < 16*NP; e += 256) {
    int rr = e/NP, n1 = e - rr*NP;
    ly4[n1*20 + rr] = xim[(((n00 + rr + 126) & 127))*NX + ((n1 + 126) & 127)];
  }
  __syncthreads();
  for (int e = tid; e < 268; e += 256) {   // 4 rowgroups x 67 v
    int rg = e/67, v = e - rg*67;
    float s0, c0; sincosf(TWO_PI*(float)v/(float)NP, &s0, &c0);
    float tr = 1.f, ti = 0.f;
    float ar0=0,ai0=0,ar1=0,ai1=0,ar2=0,ai2=0,ar3=0,ai3=0;
#pragma unroll 2
    for (int n1 = 0; n1 < NP; n1++) {
      float4 d = *(const float4*)(ly4 + n1*20 + rg*4);
      ar0 += tr*d.x; ai0 -= ti*d.x;
      ar1 += tr*d.y; ai1 -= ti*d.y;
      ar2 += tr*d.z; ai2 -= ti*d.z;
      ar3 += tr*d.w; ai3 -= ti*d.w;
      float ntr = tr*c0 - ti*s0; ti = tr*s0 + ti*c0; tr = ntr;
    }
    float arr[4] = {ar0,ar1,ar2,ar3}, aii[4] = {ai0,ai1,ai2,ai3};
#pragma unroll
    for (int q = 0; q < 4; q++) {
      int row = n00 + rg*4 + q;
      if (row < NP) A[((size_t)img*NP + row)*NV + v] = make_float2(arr[q], aii[q]);
    }
  }
}

// S2 col-DFT + H: T[v][u] = H[c][v][u] * sum_n0 A[n0][v] W^(u n0). 8-wide v-strip, 4 v/lane.
__global__ __launch_bounds__(256, 4) void k_s2(
    const float2* __restrict__ A, const float2* __restrict__ H,
    float2* __restrict__ T) {
  __shared__ float2 la[NP*10];          // [n0][j], 8 used of 10
  int tid = threadIdx.x, img = blockIdx.y, v0 = blockIdx.x*8, c = img & 63;
  for (int e = tid; e < NP*8; e += 256) {
    int n0 = e >> 3, j = e & 7, v = v0 + j;
    la[n0*10 + j] = (v < NV) ? A[((size_t)img*NP + n0)*NV + v] : make_float2(0.f, 0.f);
  }
  __syncthreads();
  for (int e = tid; e < 264; e += 256) {   // 2 jj-groups x 132 u
    int jj = e/132, u = e - jj*132;
    float s0, c0; sincosf(TWO_PI*(float)u/(float)NP, &s0, &c0);
    float tr = 1.f, ti = 0.f;
    float ar0=0,ai0=0,ar1=0,ai1=0,ar2=0,ai2=0,ar3=0,ai3=0;
#pragma unroll 2
    for (int n0 = 0; n0 < NP; n0++) {
      const float4* p = (const float4*)(la + n0*10 + jj*4);
      float4 d01 = p[0], d23 = p[1];
      ar0 += d01.x*tr + d01.y*ti;  ai0 += d01.y*tr - d01.x*ti;
      ar1 += d01.z*tr + d01.w*ti;  ai1 += d01.w*tr - d01.z*ti;
      ar2 += d23.x*tr + d23.y*ti;  ai2 += d23.y*tr - d23.x*ti;
      ar3 += d23.z*tr + d23.w*ti;  ai3 += d23.w*tr - d23.z*ti;
      float ntr = tr*c0 - ti*s0; ti = tr*s0 + ti*c0; tr = ntr;
    }
    float arr[4] = {ar0,ar1,ar2,ar3}, aii[4] = {ai0,ai1,ai2,ai3};
#pragma unroll
    for (int q = 0; q < 4; q++) {
      int v = v0 + jj*4 + q;
      if (v < NV) {
        float2 h = H[((size_t)c*NV + v)*NP + u];
        T[((size_t)img*NV + v)*NP + u] =
            make_float2(arr[q]*h.x - aii[q]*h.y, arr[q]*h.y + aii[q]*h.x);
      }
    }
  }
}

// S3 col-inverse: U[v][n0] = sum_u conj(W)^(n0 u) T[v][u]. 8-wide v-strip, 4 v/lane.
__global__ __launch_bounds__(256, 4) void k_s3(
    const float2* __restrict__ T, float2* __restrict__ U) {
  __shared__ float2 lt[NP*10];          // [u][j]
  int tid = threadIdx.x, img = blockIdx.y, v0 = blockIdx.x*8;
  for (int e = tid; e < NP*8; e += 256) {
    int j = e/132, u = e - j*132, v = v0 + j;
    lt[u*10 + j] = (v < NV) ? T[((size_t)img*NV + v)*NP + u] : make_float2(0.f, 0.f);
  }
  __syncthreads();
  for (int e = tid; e < 264; e += 256) {
    int jj = e/132, n0 = e - jj*132;
    float s0, c0; sincosf(TWO_PI*(float)n0/(float)NP, &s0, &c0);
    float tr = 1.f, ti = 0.f;
    float ar0=0,ai0=0,ar1=0,ai1=0,ar2=0,ai2=0,ar3=0,ai3=0;
#pragma unroll 2
    for (int u = 0; u < NP; u++) {
      const float4* p = (const float4*)(lt + u*10 + jj*4);
      float4 d01 = p[0], d23 = p[1];
      ar0 += d01.x*tr - d01.y*ti;  ai0 += d01.x*ti + d01.y*tr;
      ar1 += d01.z*tr - d01.w*ti;  ai1 += d01.z*ti + d01.w*tr;
      ar2 += d23.x*tr - d23.y*ti;  ai2 += d23.x*ti + d23.y*tr;
      ar3 += d23.z*tr - d23.w*ti;  ai3 += d23.z*ti + d23.w*tr;
      float ntr = tr*c0 - ti*s0; ti = tr*s0 + ti*c0; tr = ntr;
    }
    float arr[4] = {ar0,ar1,ar2,ar3}, aii[4] = {ai0,ai1,ai2,ai3};
#pragma unroll
    for (int q = 0; q < 4; q++) {
      int v = v0 + jj*4 + q;
      if (v < NV) U[((size_t)img*NV + v)*NP + n0] = make_float2(arr[q], aii[q]);
    }
  }
}

// S4 row real inverse (half-spectrum): 8 rows/block, lane = (rowgroup, n1), 4 rows/lane.
__global__ __launch_bounds__(256, 4) void k_s4(
    const float2* __restrict__ U, float* __restrict__ rho) {
  __shared__ float2 lu[NV*10];          // [v][r], 8 used of 10
  int tid = threadIdx.x, img = blockIdx.y, n00 = blockIdx.x*8;
  for (int e = tid; e < NV*8; e += 256) {
    int v = e >> 3, r = e & 7, n0 = n00 + r;
    lu[v*10 + r] = (n0 < NP) ? U[((size_t)img*NV + v)*NP + n0] : make_float2(0.f, 0.f);
  }
  __syncthreads();
  for (int e = tid; e < 264; e += 256) {
    int rg = e/132, n1 = e - rg*132;
    float s0, c0; sincosf(TWO_PI*(float)n1/(float)NP, &s0, &c0);
    float tr = c0, ti = s0;            // starts at v=1: W^(n1)
    float a0=0,a1=0,a2=0,a3=0;
#pragma unroll 2
    for (int v = 1; v < 66; v++) {
      const float4* p = (const float4*)(lu + v*10 + rg*4);
      float4 d01 = p[0], d23 = p[1];
      a0 += d01.x*tr - d01.y*ti;
      a1 += d01.z*tr - d01.w*ti;
      a2 += d23.x*tr - d23.y*ti;
      a3 += d23.z*tr - d23.w*ti;
      float ntr = tr*c0 - ti*s0; ti = tr*s0 + ti*c0; tr = ntr;
    }
    float sgn = (n1 & 1) ? -1.f : 1.f;
    float acc[4] = {a0,a1,a2,a3};
#pragma unroll
    for (int q = 0; q < 4; q++) {
      int r = rg*4 + q, row = n00 + r;
      if (row < NP) {
        float dc = lu[r].x;            // v=0
        float ny = lu[66*10 + r].x;    // v=66 Nyquist
        rho[(size_t)img*NPP + (size_t)row*NP + n1] =
            (dc + sgn*ny + 2.f*acc[q]) * (1.0f/(float)NPP);
      }
    }
  }
}

// epilogue: out = gelu( x_up + subpixel 3x3 taps of K over zero-upsampled rho )
__global__ __launch_bounds__(256) void k_epilogue(
    const float* __restrict__ x, const float* __restrict__ wgt,
    const float* __restrict__ rho, float* __restrict__ out) {
  int idx = blockIdx.x * 256 + threadIdx.x;
  int o1 = idx & 255;
  int o0 = (idx >> 8) & 255;
  int img = idx >> 16;
  int c = img & 63;
  int n0 = (o0 + 4) >> 1, n1 = (o1 + 4) >> 1;
  int p0 = o0 & 1, p1 = o1 & 1;
  const float* rim = rho + (size_t)img*NPP;
  int base = n0*NP + n1;
  float r00 = rim[base], r01 = rim[base+1], r10 = rim[base+NP], r11 = rim[base+NP+1];
  const float* w = wgt + c*9;
  float wa = p0 ? (p1 ? w[0] : w[1]) : (p1 ? w[3] : w[4]);
  float wb = p1 ? (p0 ? w[2] : w[5]) : 0.f;
  float wc = p0 ? (p1 ? w[6] : w[7]) : 0.f;
  float wd = (p0 & p1) ? w[8] : 0.f;
  float S = wa*r00 + wb*r01 + wc*r10 + wd*r11;
  float xv = x[(size_t)img*NX*NX + (n0-2)*NX + (n1-2)];
  float z = xv + S;
  out[idx] = 0.5f*z*(1.0f + erff(z*0.70710678118654752f));
}

extern "C" void kernel_launch(void* const* d_in, const int* in_sizes, int n_in,
                              void* d_out, int out_size, void* d_ws, size_t ws_size,
                              hipStream_t stream) {
  const float* x    = (const float*)d_in[0];
  const float* wgt  = (const float*)d_in[1];
  const float* bias = (const float*)d_in[2];
  float* ws = (float*)d_ws;
  float2* H   = (float2*)(ws + OFF_H);
  float2* A   = (float2*)(ws + OFF_A);
  float2* T   = (float2*)(ws + OFF_T);
  float2* U   = (float2*)(ws + OFF_U);
  float*  rho = ws + OFF_RHO;
  float* out = (float*)d_out;

  k_compute_H<<<dim3((NV*NP + 255)/256, NCH), 256, 0, stream>>>(wgt, bias, H);
  k_s1 <<<dim3(9,  NIMG), 256, 0, stream>>>(x, A);     // 9*16 >= 132 rows
  k_s2 <<<dim3(9,  NIMG), 256, 0, stream>>>(A, H, T);  // 9*8  >= 67 v
  k_s3 <<<dim3(9,  NIMG), 256, 0, stream>>>(T, U);
  k_s4 <<<dim3(17, NIMG), 256, 0, stream>>>(U, rho);   // 17*8 >= 132 rows
  k_epilogue<<<(NIMG*NO*NO)/256, 256, 0, stream>>>(x, wgt, rho, out);
}